// Round 1
// baseline (1127.896 us; speedup 1.0000x reference)
//
#include <hip/hip_runtime.h>

// out[r,g] = act( sum_{s=start[g]}^{start[g+1]-1} x[r,s]*w[s] + b[g] )
// act(z) = leaky(leaky(z,0.1),0.2) == (z>=0 ? z : 0.02*z)

__global__ void seg_bounds_kernel(const int* __restrict__ gene_ids,
                                  int* __restrict__ start, int S, int G) {
    int s = blockIdx.x * blockDim.x + threadIdx.x;
    if (s >= S) return;
    int c = gene_ids[s];
    if (s == 0) {
        for (int g = 0; g <= c; ++g) start[g] = 0;
    } else {
        int p = gene_ids[s - 1];
        for (int g = p + 1; g <= c; ++g) start[g] = s;
    }
    if (s == S - 1) {
        for (int g = c + 1; g <= G; ++g) start[g] = S;
    }
}

__global__ void gene_linear_kernel(const float* __restrict__ x,
                                   const float* __restrict__ w,
                                   const float* __restrict__ b,
                                   const int* __restrict__ start,
                                   float* __restrict__ out,
                                   int S, int G) {
    int g = blockIdx.x * blockDim.x + threadIdx.x;
    int r = blockIdx.y;
    if (g >= G) return;
    int s0 = start[g];
    int s1 = start[g + 1];
    const float* __restrict__ xr = x + (size_t)r * (size_t)S;
    float sum = 0.0f;
    for (int s = s0; s < s1; ++s) {
        sum = fmaf(xr[s], w[s], sum);
    }
    float z = sum + b[g];
    out[(size_t)r * (size_t)G + g] = (z >= 0.0f) ? z : 0.02f * z;
}

extern "C" void kernel_launch(void* const* d_in, const int* in_sizes, int n_in,
                              void* d_out, int out_size, void* d_ws, size_t ws_size,
                              hipStream_t stream) {
    const float* x        = (const float*)d_in[0];
    const float* w        = (const float*)d_in[1];
    const float* b        = (const float*)d_in[2];
    const int*   gene_ids = (const int*)d_in[3];

    const int S = in_sizes[1];
    const int G = in_sizes[2];
    const int B = in_sizes[0] / S;

    float* out = (float*)d_out;
    int* start = (int*)d_ws;  // (G+1) ints

    // 1) segment boundaries from sorted gene_ids
    {
        int threads = 256;
        int blocks = (S + threads - 1) / threads;
        seg_bounds_kernel<<<blocks, threads, 0, stream>>>(gene_ids, start, S, G);
    }

    // 2) fused segment-dot + bias + double-leaky
    {
        dim3 block(256, 1, 1);
        dim3 grid((G + 255) / 256, B, 1);
        gene_linear_kernel<<<grid, block, 0, stream>>>(x, w, b, start, out, S, G);
    }
}

// Round 2
// 408.938 us; speedup vs baseline: 2.7581x; 2.7581x over previous
//
#include <hip/hip_runtime.h>

// out[r,g] = act( sum_{s=start[g]}^{start[g+1]-1} x[r,s]*w[s] + b[g] )
// act(z) = leaky(leaky(z,0.1),0.2) == (z>=0 ? z : 0.02*z)

#define ROWS 4   // rows per thread: w reused 4x from registers, 4 independent acc chains

__global__ void seg_bounds_kernel(const int* __restrict__ gene_ids,
                                  int* __restrict__ start, int S, int G) {
    int s = blockIdx.x * blockDim.x + threadIdx.x;
    if (s >= S) return;
    int c = gene_ids[s];
    if (s == 0) {
        for (int g = 0; g <= c; ++g) start[g] = 0;
    } else {
        int p = gene_ids[s - 1];
        for (int g = p + 1; g <= c; ++g) start[g] = s;
    }
    if (s == S - 1) {
        for (int g = c + 1; g <= G; ++g) start[g] = S;
    }
}

__global__ void gene_linear_kernel(const float* __restrict__ x,
                                   const float* __restrict__ w,
                                   const float* __restrict__ b,
                                   const int* __restrict__ start,
                                   float* __restrict__ out,
                                   int S, int G) {
    int g = blockIdx.x * blockDim.x + threadIdx.x;
    if (g >= G) return;
    const int r0 = blockIdx.y * ROWS;
    const int s0 = start[g];
    const int s1 = start[g + 1];

    const float* __restrict__ x0 = x + (size_t)r0 * (size_t)S;

    float sum[ROWS];
#pragma unroll
    for (int rr = 0; rr < ROWS; ++rr) sum[rr] = 0.0f;

    int s = s0;
    // main: 8-wide chunks, all loads independent before any fma
    for (; s + 8 <= s1; s += 8) {
        float wv[8];
#pragma unroll
        for (int j = 0; j < 8; ++j) wv[j] = w[s + j];
#pragma unroll
        for (int rr = 0; rr < ROWS; ++rr) {
            const float* __restrict__ xr = x0 + (size_t)rr * (size_t)S + s;
            float xv[8];
#pragma unroll
            for (int j = 0; j < 8; ++j) xv[j] = xr[j];
#pragma unroll
            for (int j = 0; j < 8; ++j) sum[rr] = fmaf(xv[j], wv[j], sum[rr]);
        }
    }
    // tail
    for (; s < s1; ++s) {
        const float wv = w[s];
#pragma unroll
        for (int rr = 0; rr < ROWS; ++rr)
            sum[rr] = fmaf(x0[(size_t)rr * (size_t)S + s], wv, sum[rr]);
    }

    const float bias = b[g];
#pragma unroll
    for (int rr = 0; rr < ROWS; ++rr) {
        const float z = sum[rr] + bias;
        out[(size_t)(r0 + rr) * (size_t)G + g] = (z >= 0.0f) ? z : 0.02f * z;
    }
}

extern "C" void kernel_launch(void* const* d_in, const int* in_sizes, int n_in,
                              void* d_out, int out_size, void* d_ws, size_t ws_size,
                              hipStream_t stream) {
    const float* x        = (const float*)d_in[0];
    const float* w        = (const float*)d_in[1];
    const float* b        = (const float*)d_in[2];
    const int*   gene_ids = (const int*)d_in[3];

    const int S = in_sizes[1];
    const int G = in_sizes[2];
    const int B = in_sizes[0] / S;

    float* out = (float*)d_out;
    int* start = (int*)d_ws;  // (G+1) ints

    // 1) segment boundaries from sorted gene_ids
    {
        int threads = 256;
        int blocks = (S + threads - 1) / threads;
        seg_bounds_kernel<<<blocks, threads, 0, stream>>>(gene_ids, start, S, G);
    }

    // 2) fused segment-dot + bias + double-leaky, ROWS rows per thread
    {
        dim3 block(256, 1, 1);
        dim3 grid((G + 255) / 256, B / ROWS, 1);
        gene_linear_kernel<<<grid, block, 0, stream>>>(x, w, b, start, out, S, G);
    }
}

// Round 3
// 246.967 us; speedup vs baseline: 4.5670x; 1.6558x over previous
//
#include <hip/hip_runtime.h>

// out[r,g] = act( sum_{s=start[g]}^{start[g+1]-1} x[r,s]*w[s] + b[g] )
// act(z) = leaky(leaky(z,0.1),0.2) == (z>=0 ? z : 0.02*z)
//
// GROUP=8 consecutive lanes cooperate on one gene: lane l reads s = s0al+l, +8, ...
// -> each group-iteration reads a 32B-aligned contiguous chunk (coalesced),
//    vs 1 cache line per lane in the previous layout (L1-transaction-bound).

#define GROUP 8
#define ROWS 4   // rows per thread: w reused 4x, 4 independent fma chains

__global__ void seg_bounds_kernel(const int* __restrict__ gene_ids,
                                  int* __restrict__ start, int S, int G) {
    int s = blockIdx.x * blockDim.x + threadIdx.x;
    if (s >= S) return;
    int c = gene_ids[s];
    if (s == 0) {
        for (int g = 0; g <= c; ++g) start[g] = 0;
    } else {
        int p = gene_ids[s - 1];
        for (int g = p + 1; g <= c; ++g) start[g] = s;
    }
    if (s == S - 1) {
        for (int g = c + 1; g <= G; ++g) start[g] = S;
    }
}

__global__ void gene_linear_kernel(const float* __restrict__ x,
                                   const float* __restrict__ w,
                                   const float* __restrict__ b,
                                   const int* __restrict__ start,
                                   float* __restrict__ out,
                                   int S, int G, int B) {
    const int lane = threadIdx.x & (GROUP - 1);
    const int g = blockIdx.x * (blockDim.x / GROUP) + (threadIdx.x / GROUP);
    if (g >= G) return;
    const int r0 = blockIdx.y * ROWS;
    const int s0 = start[g];
    const int s1 = start[g + 1];
    const int sal = s0 & ~(GROUP - 1);   // 32B-aligned start of the group walk

    const float* __restrict__ x0 = x + (size_t)r0 * (size_t)S;

    float acc[ROWS];
#pragma unroll
    for (int rr = 0; rr < ROWS; ++rr) acc[rr] = 0.0f;

    if (r0 + ROWS <= B) {
        for (int s = sal + lane; s < s1; s += GROUP) {
            if (s >= s0) {
                const float wv = w[s];
#pragma unroll
                for (int rr = 0; rr < ROWS; ++rr)
                    acc[rr] = fmaf(x0[(size_t)rr * (size_t)S + s], wv, acc[rr]);
            }
        }
    } else {
        const int rn = B - r0;
        for (int s = sal + lane; s < s1; s += GROUP) {
            if (s >= s0) {
                const float wv = w[s];
                for (int rr = 0; rr < rn; ++rr)
                    acc[rr] = fmaf(x0[(size_t)rr * (size_t)S + s], wv, acc[rr]);
            }
        }
    }

    // reduce across the 8-lane group (xor 1,2,4 stays inside the group)
#pragma unroll
    for (int rr = 0; rr < ROWS; ++rr) {
        float v = acc[rr];
        v += __shfl_xor(v, 1);
        v += __shfl_xor(v, 2);
        v += __shfl_xor(v, 4);
        acc[rr] = v;
    }

    if (lane == 0) {
        const float bias = b[g];
        const int rn = (r0 + ROWS <= B) ? ROWS : (B - r0);
        for (int rr = 0; rr < rn; ++rr) {
            const float z = acc[rr] + bias;
            out[(size_t)(r0 + rr) * (size_t)G + g] = (z >= 0.0f) ? z : 0.02f * z;
        }
    }
}

extern "C" void kernel_launch(void* const* d_in, const int* in_sizes, int n_in,
                              void* d_out, int out_size, void* d_ws, size_t ws_size,
                              hipStream_t stream) {
    const float* x        = (const float*)d_in[0];
    const float* w        = (const float*)d_in[1];
    const float* b        = (const float*)d_in[2];
    const int*   gene_ids = (const int*)d_in[3];

    const int S = in_sizes[1];
    const int G = in_sizes[2];
    const int B = in_sizes[0] / S;

    float* out = (float*)d_out;
    int* start = (int*)d_ws;  // (G+1) ints

    // 1) segment boundaries from sorted gene_ids
    {
        int threads = 256;
        int blocks = (S + threads - 1) / threads;
        seg_bounds_kernel<<<blocks, threads, 0, stream>>>(gene_ids, start, S, G);
    }

    // 2) fused segment-dot + bias + double-leaky; 8 lanes/gene, 4 rows/thread
    {
        const int genes_per_block = 256 / GROUP;  // 32
        dim3 block(256, 1, 1);
        dim3 grid((G + genes_per_block - 1) / genes_per_block,
                  (B + ROWS - 1) / ROWS, 1);
        gene_linear_kernel<<<grid, block, 0, stream>>>(x, w, b, start, out, S, G, B);
    }
}

// Round 4
// 213.493 us; speedup vs baseline: 5.2831x; 1.1568x over previous
//
#include <hip/hip_runtime.h>

// out[r,g] = act( sum_{s=start[g]}^{start[g+1]-1} x[r,s]*w[s] + b[g] )
// act(z) = leaky(leaky(z,0.1),0.2) == (z>=0 ? z : 0.02*z)
//
// Block = 32 consecutive genes (a contiguous s-range, since gene_ids sorted)
//         x ROWS=4 batch rows.
// Phase 1: float4-coalesced load of x-range and w-range, stage products in LDS.
// Phase 2: 8 lanes/gene reduce from LDS + __shfl_xor, lane0 writes out.

#define GPB      32    // genes per block
#define ROWS     4     // batch rows per block
#define SPAN_MAX 1024  // max padded floats per row staged in LDS (16KB total)
#define NTHREADS 256

__global__ void seg_bounds_kernel(const int* __restrict__ gene_ids,
                                  int* __restrict__ start, int S, int G) {
    int s = blockIdx.x * blockDim.x + threadIdx.x;
    if (s >= S) return;
    int c = gene_ids[s];
    if (s == 0) {
        for (int g = 0; g <= c; ++g) start[g] = 0;
    } else {
        int p = gene_ids[s - 1];
        for (int g = p + 1; g <= c; ++g) start[g] = s;
    }
    if (s == S - 1) {
        for (int g = c + 1; g <= G; ++g) start[g] = S;
    }
}

__device__ inline float4 load4_safe(const float* __restrict__ p, int s, int n) {
    if (s + 4 <= n) return *(const float4*)(p + s);
    float4 v; v.x = v.y = v.z = v.w = 0.0f;
    if (s + 0 < n) v.x = p[s + 0];
    if (s + 1 < n) v.y = p[s + 1];
    if (s + 2 < n) v.z = p[s + 2];
    return v;
}

__global__ void gene_linear_kernel(const float* __restrict__ x,
                                   const float* __restrict__ w,
                                   const float* __restrict__ b,
                                   const int* __restrict__ start,
                                   float* __restrict__ out,
                                   int S, int G, int B) {
    const int tid = threadIdx.x;
    const int g0 = blockIdx.x * GPB;
    const int g1 = min(g0 + GPB, G);
    const int r0 = blockIdx.y * ROWS;
    const int rn = min(ROWS, B - r0);

    const int base    = start[g0];
    const int end     = start[g1];
    const int base_al = base & ~3;          // float4-aligned
    const int span    = end - base_al;

    __shared__ float prod[ROWS][SPAN_MAX];

    const int lane = tid & 7;
    const int g    = g0 + (tid >> 3);

    if (span <= SPAN_MAX) {
        // ---- phase 1: coalesced stream + product staging ----
        const int nv4 = (span + 3) >> 2;
        if (tid < nv4) {
            const int s = base_al + tid * 4;
            const float4 wv = load4_safe(w, s, S);
#pragma unroll
            for (int rr = 0; rr < ROWS; ++rr) {
                if (rr < rn) {
                    const float4 xv = load4_safe(x + (size_t)(r0 + rr) * (size_t)S, s, S);
                    float4 pv;
                    pv.x = xv.x * wv.x;
                    pv.y = xv.y * wv.y;
                    pv.z = xv.z * wv.z;
                    pv.w = xv.w * wv.w;
                    *(float4*)&prod[rr][tid * 4] = pv;
                }
            }
        }
        __syncthreads();

        // ---- phase 2: per-gene reduce from LDS, 8 lanes/gene ----
        if (g < g1) {
            const int ss0 = start[g];
            const int ss1 = start[g + 1];
            float acc[ROWS];
#pragma unroll
            for (int rr = 0; rr < ROWS; ++rr) acc[rr] = 0.0f;
            for (int s = ss0 + lane; s < ss1; s += 8) {
                const int o = s - base_al;
#pragma unroll
                for (int rr = 0; rr < ROWS; ++rr) acc[rr] += prod[rr][o];
            }
#pragma unroll
            for (int rr = 0; rr < ROWS; ++rr) {
                float v = acc[rr];
                v += __shfl_xor(v, 1);
                v += __shfl_xor(v, 2);
                v += __shfl_xor(v, 4);
                acc[rr] = v;
            }
            if (lane == 0) {
                const float bias = b[g];
                for (int rr = 0; rr < rn; ++rr) {
                    const float z = acc[rr] + bias;
                    out[(size_t)(r0 + rr) * (size_t)G + g] = (z >= 0.0f) ? z : 0.02f * z;
                }
            }
        }
    } else {
        // ---- fallback (span overflow — statistically never): direct reads ----
        if (g < g1) {
            const int ss0 = start[g];
            const int ss1 = start[g + 1];
            float acc[ROWS];
#pragma unroll
            for (int rr = 0; rr < ROWS; ++rr) acc[rr] = 0.0f;
            for (int s = ss0 + lane; s < ss1; s += 8) {
                const float wv = w[s];
                for (int rr = 0; rr < rn; ++rr)
                    acc[rr] = fmaf(x[(size_t)(r0 + rr) * (size_t)S + s], wv, acc[rr]);
            }
#pragma unroll
            for (int rr = 0; rr < ROWS; ++rr) {
                float v = acc[rr];
                v += __shfl_xor(v, 1);
                v += __shfl_xor(v, 2);
                v += __shfl_xor(v, 4);
                acc[rr] = v;
            }
            if (lane == 0) {
                const float bias = b[g];
                for (int rr = 0; rr < rn; ++rr) {
                    const float z = acc[rr] + bias;
                    out[(size_t)(r0 + rr) * (size_t)G + g] = (z >= 0.0f) ? z : 0.02f * z;
                }
            }
        }
    }
}

extern "C" void kernel_launch(void* const* d_in, const int* in_sizes, int n_in,
                              void* d_out, int out_size, void* d_ws, size_t ws_size,
                              hipStream_t stream) {
    const float* x        = (const float*)d_in[0];
    const float* w        = (const float*)d_in[1];
    const float* b        = (const float*)d_in[2];
    const int*   gene_ids = (const int*)d_in[3];

    const int S = in_sizes[1];
    const int G = in_sizes[2];
    const int B = in_sizes[0] / S;

    float* out = (float*)d_out;
    int* start = (int*)d_ws;  // (G+1) ints

    // 1) segment boundaries from sorted gene_ids
    {
        int threads = 256;
        int blocks = (S + threads - 1) / threads;
        seg_bounds_kernel<<<blocks, threads, 0, stream>>>(gene_ids, start, S, G);
    }

    // 2) fused segment-dot + bias + double-leaky
    {
        dim3 block(NTHREADS, 1, 1);
        dim3 grid((G + GPB - 1) / GPB, (B + ROWS - 1) / ROWS, 1);
        gene_linear_kernel<<<grid, block, 0, stream>>>(x, w, b, start, out, S, G, B);
    }
}